// Round 5
// baseline (226.036 us; speedup 1.0000x reference)
//
#include <hip/hip_runtime.h>
#include <cmath>

typedef unsigned short u16;
typedef unsigned int u32;
typedef __bf16 bf16x2 __attribute__((ext_vector_type(2)));
typedef __bf16 bf16x8 __attribute__((ext_vector_type(8)));
typedef float f32x4 __attribute__((ext_vector_type(4)));
typedef float f32x16 __attribute__((ext_vector_type(16)));

#define NQ (768*768)
#define NK (384*768)

// ---------- helpers ----------
__device__ __forceinline__ u16 f2bf(float f) {
  u32 u = __float_as_uint(f);
  u32 r = (u + 0x7FFFu + ((u >> 16) & 1u)) >> 16;  // RNE
  return (u16)r;
}
__device__ __forceinline__ u32 packbf(float a, float b) {
#if __has_builtin(__builtin_amdgcn_cvt_pk_bf16_f32)
  bf16x2 v = __builtin_amdgcn_cvt_pk_bf16_f32(a, b);
  u32 r; __builtin_memcpy(&r, &v, 4); return r;
#else
  return (u32)f2bf(a) | ((u32)f2bf(b) << 16);
#endif
}
__device__ __forceinline__ float fexp2(float x) {
#if __has_builtin(__builtin_amdgcn_exp2f)
  return __builtin_amdgcn_exp2f(x);
#else
  return exp2f(x);
#endif
}
__device__ __forceinline__ bf16x8 ldfrag(const u16* p) { bf16x8 v; __builtin_memcpy(&v, p, 16); return v; }
__device__ __forceinline__ f32x16 mfma32_(bf16x8 a, bf16x8 b, f32x16 c) {
  return __builtin_amdgcn_mfma_f32_32x32x16_bf16(a, b, c, 0, 0, 0);
}

// ---------- 1) sum(|w|) per matrix ----------
__global__ __launch_bounds__(256) void abssum_kernel(const float* __restrict__ wq, const float* __restrict__ wk,
                                                     const float* __restrict__ wv, const float* __restrict__ wo,
                                                     float* __restrict__ sums) {
  int which = blockIdx.y;
  const float* w = (which == 0) ? wq : (which == 1) ? wk : (which == 2) ? wv : wo;
  int n4 = ((which == 0 || which == 3) ? NQ : NK) >> 2;
  const float4* w4 = (const float4*)w;
  float s = 0.f;
  for (int i = blockIdx.x * blockDim.x + threadIdx.x; i < n4; i += gridDim.x * blockDim.x) {
    float4 v = w4[i];
    s += fabsf(v.x) + fabsf(v.y) + fabsf(v.z) + fabsf(v.w);
  }
  for (int off = 32; off; off >>= 1) s += __shfl_down(s, off);
  __shared__ float ls[4];
  if ((threadIdx.x & 63) == 0) ls[threadIdx.x >> 6] = s;
  __syncthreads();
  if (threadIdx.x == 0) atomicAdd(&sums[which], ls[0] + ls[1] + ls[2] + ls[3]);
}

// ---------- 2) ternary quantize to bf16 {-1,0,1} ----------
__global__ __launch_bounds__(256) void quant_kernel(const float* __restrict__ wq, const float* __restrict__ wk,
                                                    const float* __restrict__ wv, const float* __restrict__ wo,
                                                    const float* __restrict__ sums,
                                                    u16* __restrict__ qw, u16* __restrict__ woq) {
  float thr0 = 0.7f * sums[0] * (1.f / NQ);
  float thr1 = 0.7f * sums[1] * (1.f / NK);
  float thr2 = 0.7f * sums[2] * (1.f / NK);
  float thr3 = 0.7f * sums[3] * (1.f / NQ);
  const int NQKV = NQ + 2 * NK;
  const int total = NQKV + NQ;
  for (int i = blockIdx.x * blockDim.x + threadIdx.x; i < total; i += gridDim.x * blockDim.x) {
    float v, th; u16* dst;
    if (i < NQ)            { v = wq[i];            th = thr0; dst = &qw[i]; }
    else if (i < NQ + NK)  { v = wk[i - NQ];       th = thr1; dst = &qw[i]; }
    else if (i < NQKV)     { v = wv[i - NQ - NK];  th = thr2; dst = &qw[i]; }
    else                   { v = wo[i - NQKV];     th = thr3; dst = &woq[i - NQKV]; }
    float q = (fabsf(v) >= th) ? ((v > 0.f) ? 1.f : -1.f) : 0.f;
    *dst = f2bf(q);
  }
}

// ---------- 3) x -> bf16 ----------
__global__ __launch_bounds__(256) void castx_kernel(const float* __restrict__ x, u16* __restrict__ xb) {
  int i = blockIdx.x * blockDim.x + threadIdx.x;
  float4 v = ((const float4*)x)[i];
  u16 o[4] = { f2bf(v.x), f2bf(v.y), f2bf(v.z), f2bf(v.w) };
  __builtin_memcpy(&xb[i * 4], o, 8);
}

// ---------- shared GEMM core: C[64m x 128n] += A[m][k] * B[n][k], K=768 ----------
__device__ __forceinline__ void gemm_tile_64x128(const u16* __restrict__ A, const u16* __restrict__ Bw,
                                                 u16* Bt, int tm, int tn, f32x16 acc[2]) {
  int t = threadIdx.x, lane = t & 63, w = t >> 6, c = lane & 31, g2 = lane >> 5;
  int wm = w & 1, wn = w >> 1;
  const u16* arow = A + (tm * 64 + wm * 32 + c) * 768;
  for (int k0 = 0; k0 < 768; k0 += 64) {
#pragma unroll
    for (int rd = 0; rd < 4; rd++) {
      int ch = (rd * 4 + w) * 64 + lane;          // 16B chunk index in [0,1024)
      int n = ch >> 3, jp = ch & 7;
      int jl = jp ^ (n & 7);                      // logical k-chunk for this physical slot
      const u16* gp = Bw + (tn * 128 + n) * 768 + k0 + jl * 8;
      __builtin_amdgcn_global_load_lds((const __attribute__((address_space(1))) u32*)gp,
                                       (__attribute__((address_space(3))) u32*)(Bt + (rd * 4 + w) * 512),
                                       16, 0, 0);
    }
    bf16x8 af[4];
#pragma unroll
    for (int ks = 0; ks < 4; ks++) af[ks] = ldfrag(arow + k0 + ks * 16 + g2 * 8);
    __syncthreads();
#pragma unroll
    for (int ks = 0; ks < 4; ks++) {
#pragma unroll
      for (int nb = 0; nb < 2; nb++) {
        int n = wn * 64 + nb * 32 + c;
        int jp = (ks * 2 + g2) ^ (n & 7);
        bf16x8 bf = ldfrag(Bt + n * 64 + jp * 8);
        acc[nb] = mfma32_(af[ks], bf, acc[nb]);
      }
    }
    __syncthreads();
  }
}

// ---------- 4) fused QKV GEMM + scale + RoPE + permuted-V transpose ----------
__global__ __launch_bounds__(256, 4) void gemm_qkv_kernel(const u16* __restrict__ xb, const u16* __restrict__ qw,
                                                          const float* __restrict__ sums,
                                                          u16* __restrict__ qb, u16* __restrict__ kb,
                                                          u16* __restrict__ vT) {
  __shared__ u16 Bt[8192];
  int tn = blockIdx.x, tm = blockIdx.y;
  f32x16 acc[2]; acc[0] = (f32x16)0.f; acc[1] = (f32x16)0.f;
  gemm_tile_64x128(xb, qw, Bt, tm, tn, acc);
  int t = threadIdx.x, lane = t & 63, w = t >> 6, c = lane & 31, g2 = lane >> 5;
  int wm = w & 1, wn = w >> 1;
  float sq = sums[0] * (1.f / NQ) * 0.180336880111120f;  // * 0.125 * log2(e)
  float sk = sums[1] * (1.f / NK);
  float sv = sums[2] * (1.f / NK);
  int mb = tm * 64 + wm * 32 + 4 * g2;
  if (tn < 9) {
    float sc = (tn < 6) ? sq : sk;
    u16* outp = (tn < 6) ? qb : kb;
    int head = (tn < 6) ? (tn * 2 + wn) : ((tn - 6) * 2 + wn);
    int stride = (tn < 6) ? 768 : 384;
    float f = fexp2((float)c * -0.41524101186092029f);   // 10000^(-c/32)
#pragma unroll
    for (int r = 0; r < 16; r++) {
      int m = mb + (r & 3) + 8 * (r >> 2);
      int s = m & 2047;
      float sn, cs; sincosf((float)s * f, &sn, &cs);
      float x1 = acc[0][r] * sc, x2 = acc[1][r] * sc;
      outp[m * stride + head * 64 + c]      = f2bf(x1 * cs - x2 * sn);
      outp[m * stride + head * 64 + c + 32] = f2bf(x2 * cs + x1 * sn);
    }
  } else {
    int kvh = (tn - 9) * 2 + wn;
#pragma unroll
    for (int nb = 0; nb < 2; nb++)
#pragma unroll
      for (int r = 0; r < 16; r++) {
        int m = mb + (r & 3) + 8 * (r >> 2);
        int bb = m >> 11, s = m & 2047;
        int sp = (s & ~12) | ((s & 4) << 1) | ((s & 8) >> 1);   // swap bits 2,3
        vT[((bb * 6 + kvh) * 64 + nb * 32 + c) * 2048 + sp] = f2bf(acc[nb][r] * sv);
      }
  }
}

// ---------- 5) attention: 32-q-per-block, barrier-free main loop, no cross-lane exchange ----------
// grid (64 q-tiles of 32 rows, 24 b*h). block 256 = 4 waves; wave w: keys [w*512, w*512+512).
// Per-wave regs ~140 (S 32 + O 32 + kf 16 + vf 16 + qf 8 + PA 8 + addr) -> fits (256,3) without spill.
__global__ __launch_bounds__(256, 3) void attn_kernel(const u16* __restrict__ qb, const u16* __restrict__ kb,
                                                      const u16* __restrict__ vT, u16* __restrict__ ab) {
  __shared__ float Obuf[4][32][66];
  __shared__ float Lbuf[4][32];
  int qt = blockIdx.x, bh = blockIdx.y;
  int b = bh / 12, h = bh % 12, kvh = h >> 1;
  int t = threadIdx.x, lane = t & 63, w = t >> 6, c = lane & 31, g2 = lane >> 5;

  const u16* qbase = qb + (b * 2048 + qt * 32) * 768 + h * 64;
  bf16x8 qf[4];
#pragma unroll
  for (int ks = 0; ks < 4; ks++)
    qf[ks] = ldfrag(qbase + c * 768 + ks * 16 + 8 * g2);

  f32x16 fz = (f32x16)0.f;
  f32x16 O[2] = {fz, fz};   // [dn]
  float lsum = 0.f;

  const u16* kbase = kb + (b * 2048) * 384 + kvh * 64;
  const u16* vbase = vT + ((b * 6 + kvh) * 64) * 2048;

  for (int it = 0; it < 8; it++) {
    int key0 = w * 512 + it * 64;
    bf16x8 kf[2][4];
#pragma unroll
    for (int km = 0; km < 2; km++)
#pragma unroll
      for (int ks = 0; ks < 4; ks++)
        kf[km][ks] = ldfrag(kbase + (key0 + km * 32 + c) * 384 + ks * 16 + 8 * g2);
    f32x16 S[2] = {fz, fz};
#pragma unroll
    for (int ks = 0; ks < 4; ks++)
#pragma unroll
      for (int km = 0; km < 2; km++)
        S[km] = mfma32_(kf[km][ks], qf[ks], S[km]);
    bf16x8 vf[2][4];
#pragma unroll
    for (int dn = 0; dn < 2; dn++)
#pragma unroll
      for (int ks = 0; ks < 4; ks++)
        vf[dn][ks] = ldfrag(vbase + (dn * 32 + c) * 2048 + key0 + ks * 16 + 8 * g2);
    // exp2 -> pack: registers ARE the PV A-frags (vT key-permuted to match C-layout ownership)
    bf16x8 PA[4];
#pragma unroll
    for (int km = 0; km < 2; km++) {
      float e[16];
#pragma unroll
      for (int r = 0; r < 16; r++) {
        e[r] = fexp2(S[km][r]);
        lsum += e[r];
      }
      u32 P[8];
#pragma unroll
      for (int j = 0; j < 8; j++) P[j] = packbf(e[2 * j], e[2 * j + 1]);
      __builtin_memcpy(&PA[km * 2 + 0], &P[0], 16);
      __builtin_memcpy(&PA[km * 2 + 1], &P[4], 16);
    }
#pragma unroll
    for (int ks = 0; ks < 4; ks++)
#pragma unroll
      for (int dn = 0; dn < 2; dn++)
        O[dn] = mfma32_(PA[ks], vf[dn][ks], O[dn]);
  }
  lsum += __shfl_xor(lsum, 32);
  if (g2 == 0) Lbuf[w][c] = lsum;
#pragma unroll
  for (int dn = 0; dn < 2; dn++)
#pragma unroll
    for (int r = 0; r < 16; r++) {
      int qq = (r & 3) + 8 * (r >> 2) + 4 * g2;
      Obuf[w][qq][dn * 32 + c] = O[dn][r];
    }
  __syncthreads();
  // epilogue: thread t -> q = t>>3, 8 d values
  {
    int qq = t >> 3, dc = (t & 7) * 8;
    float l = Lbuf[0][qq] + Lbuf[1][qq] + Lbuf[2][qq] + Lbuf[3][qq];
    float inv = 1.f / l;
    u16 o[8];
#pragma unroll
    for (int j = 0; j < 8; j++) {
      float s = Obuf[0][qq][dc + j] + Obuf[1][qq][dc + j] + Obuf[2][qq][dc + j] + Obuf[3][qq][dc + j];
      o[j] = f2bf(s * inv);
    }
    __builtin_memcpy(ab + (b * 2048 + qt * 32 + qq) * 768 + h * 64 + dc, o, 16);
  }
}

// ---------- 6) output projection GEMM -> fp32 ----------
__global__ __launch_bounds__(256, 4) void gemm_out_kernel(const u16* __restrict__ ab, const u16* __restrict__ woq,
                                                          const float* __restrict__ sums, float* __restrict__ out) {
  __shared__ u16 Bt[8192];
  int tn = blockIdx.x, tm = blockIdx.y;
  f32x16 acc[2]; acc[0] = (f32x16)0.f; acc[1] = (f32x16)0.f;
  gemm_tile_64x128(ab, woq, Bt, tm, tn, acc);
  int t = threadIdx.x, lane = t & 63, w = t >> 6, c = lane & 31, g2 = lane >> 5;
  int wm = w & 1, wn = w >> 1;
  float so = sums[3] * (1.f / NQ);
  int mb = tm * 64 + wm * 32 + 4 * g2;
#pragma unroll
  for (int nb = 0; nb < 2; nb++)
#pragma unroll
    for (int r = 0; r < 16; r++) {
      int m = mb + (r & 3) + 8 * (r >> 2);
      out[m * 768 + tn * 128 + wn * 64 + nb * 32 + c] = acc[nb][r] * so;
    }
}

// ---------- launch ----------
extern "C" void kernel_launch(void* const* d_in, const int* in_sizes, int n_in,
                              void* d_out, int out_size, void* d_ws, size_t ws_size,
                              hipStream_t stream) {
  const float* x  = (const float*)d_in[0];
  const float* wq = (const float*)d_in[1];
  const float* wk = (const float*)d_in[2];
  const float* wv = (const float*)d_in[3];
  const float* wo = (const float*)d_in[4];
  float* out = (float*)d_out;
  char* ws = (char*)d_ws;

  float* sums = (float*)ws;                    // 16 B
  u16* qw  = (u16*)(ws + 256);                 // [1536][768]
  u16* woq = (u16*)(ws + 2359552);             // [768][768]
  u16* xb  = (u16*)(ws + 3539200);             // [4096][768]
  u16* qb  = (u16*)(ws + 9830656);             // [4096][768]
  u16* kb  = (u16*)(ws + 16122112);            // [4096][384]
  u16* vT  = (u16*)(ws + 19267840);            // [2*6][64][2048] (key-permuted)
  u16* ab  = (u16*)(ws + 22413568);            // [4096][768]

  hipMemsetAsync(sums, 0, 16, stream);
  dim3 blk(256);
  abssum_kernel<<<dim3(64, 4), blk, 0, stream>>>(wq, wk, wv, wo, sums);
  quant_kernel<<<dim3(6912), blk, 0, stream>>>(wq, wk, wv, wo, sums, qw, woq);
  castx_kernel<<<dim3(3072), blk, 0, stream>>>(x, xb);
  gemm_qkv_kernel<<<dim3(12, 64), blk, 0, stream>>>(xb, qw, sums, qb, kb, vT);
  attn_kernel<<<dim3(64, 24), blk, 0, stream>>>(qb, kb, vT, ab);
  gemm_out_kernel<<<dim3(6, 64), blk, 0, stream>>>(ab, woq, sums, out);
}

// Round 6
// 172.182 us; speedup vs baseline: 1.3128x; 1.3128x over previous
//
#include <hip/hip_runtime.h>
#include <cmath>

typedef unsigned short u16;
typedef unsigned int u32;
typedef __bf16 bf16x2 __attribute__((ext_vector_type(2)));
typedef __bf16 bf16x8 __attribute__((ext_vector_type(8)));
typedef float f32x4 __attribute__((ext_vector_type(4)));
typedef float f32x16 __attribute__((ext_vector_type(16)));

#define NQ (768*768)
#define NK (384*768)

// ---------- helpers ----------
__device__ __forceinline__ u16 f2bf(float f) {
  u32 u = __float_as_uint(f);
  u32 r = (u + 0x7FFFu + ((u >> 16) & 1u)) >> 16;  // RNE
  return (u16)r;
}
__device__ __forceinline__ u32 packbf(float a, float b) {
#if __has_builtin(__builtin_amdgcn_cvt_pk_bf16_f32)
  bf16x2 v = __builtin_amdgcn_cvt_pk_bf16_f32(a, b);
  u32 r; __builtin_memcpy(&r, &v, 4); return r;
#else
  return (u32)f2bf(a) | ((u32)f2bf(b) << 16);
#endif
}
__device__ __forceinline__ float fexp2(float x) {
#if __has_builtin(__builtin_amdgcn_exp2f)
  return __builtin_amdgcn_exp2f(x);
#else
  return exp2f(x);
#endif
}
__device__ __forceinline__ bf16x8 ldfrag(const u16* p) { bf16x8 v; __builtin_memcpy(&v, p, 16); return v; }
__device__ __forceinline__ f32x16 mfma32_(bf16x8 a, bf16x8 b, f32x16 c) {
  return __builtin_amdgcn_mfma_f32_32x32x16_bf16(a, b, c, 0, 0, 0);
}

// Fragment-tiled layouts (attn reads become base + lane*16B, fully coalesced):
// K':  per (b,kvh) 131072 els: [s>>6][ (s>>5)&1 ][ d>>4 ][ lane=(s&31)+32*((d>>3)&1) ][ d&7 ]
// V':  per (b,kvh) 131072 els: [ p>>6 ][ d>>5 ][ (p>>4)&3 ][ lane=(d&31)+32*((p>>3)&1) ][ p&7 ]  (p = sigma(s))
// Q':  [ b ][ s>>5 ][ h ][ d>>4 ][ lane=(s&31)+32*((d>>3)&1) ][ d&7 ]
__device__ __forceinline__ int kidx(int b6kvh, int s, int d) {
  return b6kvh * 131072 + (s >> 6) * 4096 + ((s >> 5) & 1) * 2048 + (d >> 4) * 512 +
         ((s & 31) + 32 * ((d >> 3) & 1)) * 8 + (d & 7);
}
__device__ __forceinline__ int qidx(int b, int s, int h, int d) {
  return ((b * 64 + (s >> 5)) * 12 + h) * 2048 + (d >> 4) * 512 +
         ((s & 31) + 32 * ((d >> 3) & 1)) * 8 + (d & 7);
}
__device__ __forceinline__ int vidx(int b6kvh, int d, int p) {
  return b6kvh * 131072 + (p >> 6) * 4096 + (d >> 5) * 2048 + ((p >> 4) & 3) * 512 +
         ((d & 31) + 32 * ((p >> 3) & 1)) * 8 + (p & 7);
}

// ---------- 1) sum(|w|) per matrix ----------
__global__ __launch_bounds__(256) void abssum_kernel(const float* __restrict__ wq, const float* __restrict__ wk,
                                                     const float* __restrict__ wv, const float* __restrict__ wo,
                                                     float* __restrict__ sums) {
  int which = blockIdx.y;
  const float* w = (which == 0) ? wq : (which == 1) ? wk : (which == 2) ? wv : wo;
  int n4 = ((which == 0 || which == 3) ? NQ : NK) >> 2;
  const float4* w4 = (const float4*)w;
  float s = 0.f;
  for (int i = blockIdx.x * blockDim.x + threadIdx.x; i < n4; i += gridDim.x * blockDim.x) {
    float4 v = w4[i];
    s += fabsf(v.x) + fabsf(v.y) + fabsf(v.z) + fabsf(v.w);
  }
  for (int off = 32; off; off >>= 1) s += __shfl_down(s, off);
  __shared__ float ls[4];
  if ((threadIdx.x & 63) == 0) ls[threadIdx.x >> 6] = s;
  __syncthreads();
  if (threadIdx.x == 0) atomicAdd(&sums[which], ls[0] + ls[1] + ls[2] + ls[3]);
}

// ---------- 2) ternary quantize to bf16 {-1,0,1} ----------
__global__ __launch_bounds__(256) void quant_kernel(const float* __restrict__ wq, const float* __restrict__ wk,
                                                    const float* __restrict__ wv, const float* __restrict__ wo,
                                                    const float* __restrict__ sums,
                                                    u16* __restrict__ qw, u16* __restrict__ woq) {
  float thr0 = 0.7f * sums[0] * (1.f / NQ);
  float thr1 = 0.7f * sums[1] * (1.f / NK);
  float thr2 = 0.7f * sums[2] * (1.f / NK);
  float thr3 = 0.7f * sums[3] * (1.f / NQ);
  const int NQKV = NQ + 2 * NK;
  const int total = NQKV + NQ;
  for (int i = blockIdx.x * blockDim.x + threadIdx.x; i < total; i += gridDim.x * blockDim.x) {
    float v, th; u16* dst;
    if (i < NQ)            { v = wq[i];            th = thr0; dst = &qw[i]; }
    else if (i < NQ + NK)  { v = wk[i - NQ];       th = thr1; dst = &qw[i]; }
    else if (i < NQKV)     { v = wv[i - NQ - NK];  th = thr2; dst = &qw[i]; }
    else                   { v = wo[i - NQKV];     th = thr3; dst = &woq[i - NQKV]; }
    float q = (fabsf(v) >= th) ? ((v > 0.f) ? 1.f : -1.f) : 0.f;
    *dst = f2bf(q);
  }
}

// ---------- 3) x -> bf16 ----------
__global__ __launch_bounds__(256) void castx_kernel(const float* __restrict__ x, u16* __restrict__ xb) {
  int i = blockIdx.x * blockDim.x + threadIdx.x;
  float4 v = ((const float4*)x)[i];
  u16 o[4] = { f2bf(v.x), f2bf(v.y), f2bf(v.z), f2bf(v.w) };
  __builtin_memcpy(&xb[i * 4], o, 8);
}

// ---------- shared GEMM core: C[64m x 128n] += A[m][k] * B[n][k], K=768 ----------
__device__ __forceinline__ void gemm_tile_64x128(const u16* __restrict__ A, const u16* __restrict__ Bw,
                                                 u16* Bt, int tm, int tn, f32x16 acc[2]) {
  int t = threadIdx.x, lane = t & 63, w = t >> 6, c = lane & 31, g2 = lane >> 5;
  int wm = w & 1, wn = w >> 1;
  const u16* arow = A + (tm * 64 + wm * 32 + c) * 768;
  for (int k0 = 0; k0 < 768; k0 += 64) {
#pragma unroll
    for (int rd = 0; rd < 4; rd++) {
      int ch = (rd * 4 + w) * 64 + lane;          // 16B chunk index in [0,1024)
      int n = ch >> 3, jp = ch & 7;
      int jl = jp ^ (n & 7);                      // logical k-chunk for this physical slot
      const u16* gp = Bw + (tn * 128 + n) * 768 + k0 + jl * 8;
      __builtin_amdgcn_global_load_lds((const __attribute__((address_space(1))) u32*)gp,
                                       (__attribute__((address_space(3))) u32*)(Bt + (rd * 4 + w) * 512),
                                       16, 0, 0);
    }
    bf16x8 af[4];
#pragma unroll
    for (int ks = 0; ks < 4; ks++) af[ks] = ldfrag(arow + k0 + ks * 16 + g2 * 8);
    __syncthreads();
#pragma unroll
    for (int ks = 0; ks < 4; ks++) {
#pragma unroll
      for (int nb = 0; nb < 2; nb++) {
        int n = wn * 64 + nb * 32 + c;
        int jp = (ks * 2 + g2) ^ (n & 7);
        bf16x8 bf = ldfrag(Bt + n * 64 + jp * 8);
        acc[nb] = mfma32_(af[ks], bf, acc[nb]);
      }
    }
    __syncthreads();
  }
}

// ---------- 4) fused QKV GEMM + scale + RoPE + fragment-tiled outputs ----------
// N layout: tn 0..5 = Q (head = 2tn+wn), 6..8 = K (kvh = 2(tn-6)+wn), 9..11 = V (kvh = 2(tn-9)+wn).
// Q additionally scaled by 0.125*log2(e) so attention uses raw exp2.
// V stored with key index bits 2<->3 swapped (sigma) so attn's PV A-frag needs no lane exchange.
__global__ __launch_bounds__(256, 4) void gemm_qkv_kernel(const u16* __restrict__ xb, const u16* __restrict__ qw,
                                                          const float* __restrict__ sums,
                                                          u16* __restrict__ qb, u16* __restrict__ kb,
                                                          u16* __restrict__ vT) {
  __shared__ u16 Bt[8192];
  int tn = blockIdx.x, tm = blockIdx.y;
  f32x16 acc[2]; acc[0] = (f32x16)0.f; acc[1] = (f32x16)0.f;
  gemm_tile_64x128(xb, qw, Bt, tm, tn, acc);
  int t = threadIdx.x, lane = t & 63, w = t >> 6, c = lane & 31, g2 = lane >> 5;
  int wm = w & 1, wn = w >> 1;
  float sq = sums[0] * (1.f / NQ) * 0.180336880111120f;  // * 0.125 * log2(e)
  float sk = sums[1] * (1.f / NK);
  float sv = sums[2] * (1.f / NK);
  int mb = tm * 64 + wm * 32 + 4 * g2;
  if (tn < 9) {
    float sc = (tn < 6) ? sq : sk;
    int head = (tn < 6) ? (tn * 2 + wn) : ((tn - 6) * 2 + wn);
    float f = fexp2((float)c * -0.41524101186092029f);   // 10000^(-c/32)
#pragma unroll
    for (int r = 0; r < 16; r++) {
      int m = mb + (r & 3) + 8 * (r >> 2);
      int bb = m >> 11, s = m & 2047;
      float sn, cs; sincosf((float)s * f, &sn, &cs);
      float x1 = acc[0][r] * sc, x2 = acc[1][r] * sc;
      u16 y1 = f2bf(x1 * cs - x2 * sn);       // dim d = c
      u16 y2 = f2bf(x2 * cs + x1 * sn);       // dim d = c + 32
      if (tn < 6) {
        qb[qidx(bb, s, head, c)]      = y1;
        qb[qidx(bb, s, head, c + 32)] = y2;
      } else {
        kb[kidx(bb * 6 + head, s, c)]      = y1;
        kb[kidx(bb * 6 + head, s, c + 32)] = y2;
      }
    }
  } else {
    int kvh = (tn - 9) * 2 + wn;
#pragma unroll
    for (int nb = 0; nb < 2; nb++)
#pragma unroll
      for (int r = 0; r < 16; r++) {
        int m = mb + (r & 3) + 8 * (r >> 2);
        int bb = m >> 11, s = m & 2047;
        int sp = (s & ~12) | ((s & 4) << 1) | ((s & 8) >> 1);   // sigma: swap bits 2,3
        vT[vidx(bb * 6 + kvh, nb * 32 + c, sp)] = f2bf(acc[nb][r] * sv);
      }
  }
}

// ---------- 5) attention: GQA-pair blocks, coalesced fragment loads, barrier-free main loop ----------
// grid (64 q-tiles of 32 rows, 12 b*kvh). block 256 = 4 waves; wave w: keys [w*512, w*512+512).
// Each block computes BOTH heads (2kvh, 2kvh+1) sharing this kvh -> K/V loaded once for 2 heads.
// S^T = K Q^T (C cols = q). V's key permutation makes exp2(S) registers directly the PV A-frags.
__global__ __launch_bounds__(256, 2) void attn_kernel(const u16* __restrict__ qb, const u16* __restrict__ kb,
                                                      const u16* __restrict__ vT, u16* __restrict__ ab) {
  __shared__ float Obuf[4][32][66];
  __shared__ float Lbuf[2][4][32];
  int qt = blockIdx.x, bk = blockIdx.y;
  int b = bk / 6, kvh = bk % 6;
  int b6kvh = bk;
  int t = threadIdx.x, lane = t & 63, w = t >> 6, c = lane & 31, g2 = lane >> 5;

  // Q B-frags for both heads of the group (coalesced: base + lane*16B)
  bf16x8 qf[2][4];
#pragma unroll
  for (int qn = 0; qn < 2; qn++) {
    const u16* qbase = qb + ((b * 64 + qt) * 12 + (kvh * 2 + qn)) * 2048;
#pragma unroll
    for (int ks = 0; ks < 4; ks++)
      qf[qn][ks] = ldfrag(qbase + ks * 512 + lane * 8);
  }

  f32x16 fz = (f32x16)0.f;
  f32x16 O[2][2] = {{fz, fz}, {fz, fz}};   // [qn][dn]
  float lsum[2] = {0.f, 0.f};

  const u16* kvbaseK = kb + b6kvh * 131072;
  const u16* kvbaseV = vT + b6kvh * 131072;

  for (int it = 0; it < 8; it++) {
    int kb64 = w * 8 + it;                 // 64-key tile index
    const u16* kt = kvbaseK + kb64 * 4096;
    const u16* vt = kvbaseV + kb64 * 4096;
    bf16x8 kf[2][4];
#pragma unroll
    for (int km = 0; km < 2; km++)
#pragma unroll
      for (int ks = 0; ks < 4; ks++)
        kf[km][ks] = ldfrag(kt + km * 2048 + ks * 512 + lane * 8);
    f32x16 S[2][2] = {{fz, fz}, {fz, fz}};
#pragma unroll
    for (int ks = 0; ks < 4; ks++)
#pragma unroll
      for (int km = 0; km < 2; km++)
#pragma unroll
        for (int qn = 0; qn < 2; qn++)
          S[km][qn] = mfma32_(kf[km][ks], qf[qn][ks], S[km][qn]);
    bf16x8 vf[2][4];
#pragma unroll
    for (int dn = 0; dn < 2; dn++)
#pragma unroll
      for (int ks = 0; ks < 4; ks++)
        vf[dn][ks] = ldfrag(vt + dn * 2048 + ks * 512 + lane * 8);
    // exp2 -> pack: registers ARE the PV A-frags (V key-permuted to match C-layout ownership)
    bf16x8 PA[2][4];
#pragma unroll
    for (int qn = 0; qn < 2; qn++) {
#pragma unroll
      for (int km = 0; km < 2; km++) {
        float e[16];
#pragma unroll
        for (int r = 0; r < 16; r++) {
          e[r] = fexp2(S[km][qn][r]);
          lsum[qn] += e[r];
        }
        u32 P[8];
#pragma unroll
        for (int j = 0; j < 8; j++) P[j] = packbf(e[2 * j], e[2 * j + 1]);
        __builtin_memcpy(&PA[qn][km * 2 + 0], &P[0], 16);
        __builtin_memcpy(&PA[qn][km * 2 + 1], &P[4], 16);
      }
    }
#pragma unroll
    for (int ks = 0; ks < 4; ks++)
#pragma unroll
      for (int qn = 0; qn < 2; qn++)
#pragma unroll
        for (int dn = 0; dn < 2; dn++)
          O[qn][dn] = mfma32_(PA[qn][ks], vf[dn][ks], O[qn][dn]);
  }
#pragma unroll
  for (int qn = 0; qn < 2; qn++) lsum[qn] += __shfl_xor(lsum[qn], 32);
  if (g2 == 0) { Lbuf[0][w][c] = lsum[0]; Lbuf[1][w][c] = lsum[1]; }
  // two-phase combine over the two heads (halves LDS)
#pragma unroll
  for (int qn = 0; qn < 2; qn++) {
    if (qn) __syncthreads();
#pragma unroll
    for (int dn = 0; dn < 2; dn++)
#pragma unroll
      for (int r = 0; r < 16; r++) {
        int qq = (r & 3) + 8 * (r >> 2) + 4 * g2;
        Obuf[w][qq][dn * 32 + c] = O[qn][dn][r];
      }
    __syncthreads();
    int qq = t >> 3, dc = (t & 7) * 8;
    float l = Lbuf[qn][0][qq] + Lbuf[qn][1][qq] + Lbuf[qn][2][qq] + Lbuf[qn][3][qq];
    float inv = 1.f / l;
    u16 o[8];
#pragma unroll
    for (int j = 0; j < 8; j++) {
      float s = Obuf[0][qq][dc + j] + Obuf[1][qq][dc + j] + Obuf[2][qq][dc + j] + Obuf[3][qq][dc + j];
      o[j] = f2bf(s * inv);
    }
    __builtin_memcpy(ab + (b * 2048 + qt * 32 + qq) * 768 + (kvh * 2 + qn) * 64 + dc, o, 16);
  }
}

// ---------- 6) output projection GEMM -> fp32 ----------
__global__ __launch_bounds__(256, 4) void gemm_out_kernel(const u16* __restrict__ ab, const u16* __restrict__ woq,
                                                          const float* __restrict__ sums, float* __restrict__ out) {
  __shared__ u16 Bt[8192];
  int tn = blockIdx.x, tm = blockIdx.y;
  f32x16 acc[2]; acc[0] = (f32x16)0.f; acc[1] = (f32x16)0.f;
  gemm_tile_64x128(ab, woq, Bt, tm, tn, acc);
  int t = threadIdx.x, lane = t & 63, w = t >> 6, c = lane & 31, g2 = lane >> 5;
  int wm = w & 1, wn = w >> 1;
  float so = sums[3] * (1.f / NQ);
  int mb = tm * 64 + wm * 32 + 4 * g2;
#pragma unroll
  for (int nb = 0; nb < 2; nb++)
#pragma unroll
    for (int r = 0; r < 16; r++) {
      int m = mb + (r & 3) + 8 * (r >> 2);
      out[m * 768 + tn * 128 + wn * 64 + nb * 32 + c] = acc[nb][r] * so;
    }
}

// ---------- launch ----------
extern "C" void kernel_launch(void* const* d_in, const int* in_sizes, int n_in,
                              void* d_out, int out_size, void* d_ws, size_t ws_size,
                              hipStream_t stream) {
  const float* x  = (const float*)d_in[0];
  const float* wq = (const float*)d_in[1];
  const float* wk = (const float*)d_in[2];
  const float* wv = (const float*)d_in[3];
  const float* wo = (const float*)d_in[4];
  float* out = (float*)d_out;
  char* ws = (char*)d_ws;

  float* sums = (float*)ws;                    // 16 B
  u16* qw  = (u16*)(ws + 256);                 // [1536][768]
  u16* woq = (u16*)(ws + 2359552);             // [768][768]
  u16* xb  = (u16*)(ws + 3539200);             // [4096][768]
  u16* qb  = (u16*)(ws + 9830656);             // Q' fragment-tiled (3.1M els)
  u16* kb  = (u16*)(ws + 16122112);            // K' fragment-tiled (1.57M els)
  u16* vT  = (u16*)(ws + 19267840);            // V' fragment-tiled, key-permuted (1.57M els)
  u16* ab  = (u16*)(ws + 22413568);            // [4096][768]

  hipMemsetAsync(sums, 0, 16, stream);
  dim3 blk(256);
  abssum_kernel<<<dim3(64, 4), blk, 0, stream>>>(wq, wk, wv, wo, sums);
  quant_kernel<<<dim3(6912), blk, 0, stream>>>(wq, wk, wv, wo, sums, qw, woq);
  castx_kernel<<<dim3(3072), blk, 0, stream>>>(x, xb);
  gemm_qkv_kernel<<<dim3(12, 64), blk, 0, stream>>>(xb, qw, sums, qb, kb, vT);
  attn_kernel<<<dim3(64, 12), blk, 0, stream>>>(qb, kb, vT, ab);
  gemm_out_kernel<<<dim3(6, 64), blk, 0, stream>>>(ab, woq, sums, out);
}

// Round 7
// 157.470 us; speedup vs baseline: 1.4354x; 1.0934x over previous
//
#include <hip/hip_runtime.h>
#include <cmath>

typedef unsigned short u16;
typedef unsigned int u32;
typedef __bf16 bf16x2 __attribute__((ext_vector_type(2)));
typedef __bf16 bf16x8 __attribute__((ext_vector_type(8)));
typedef float f32x16 __attribute__((ext_vector_type(16)));

#define NQ (768*768)
#define NK (384*768)

// ---------- helpers ----------
__device__ __forceinline__ u16 f2bf(float f) {
  u32 u = __float_as_uint(f);
  u32 r = (u + 0x7FFFu + ((u >> 16) & 1u)) >> 16;  // RNE
  return (u16)r;
}
__device__ __forceinline__ u32 packbf(float a, float b) {
#if __has_builtin(__builtin_amdgcn_cvt_pk_bf16_f32)
  bf16x2 v = __builtin_amdgcn_cvt_pk_bf16_f32(a, b);
  u32 r; __builtin_memcpy(&r, &v, 4); return r;
#else
  return (u32)f2bf(a) | ((u32)f2bf(b) << 16);
#endif
}
__device__ __forceinline__ float fexp2(float x) {
#if __has_builtin(__builtin_amdgcn_exp2f)
  return __builtin_amdgcn_exp2f(x);
#else
  return exp2f(x);
#endif
}
__device__ __forceinline__ bf16x8 ldfrag(const u16* p) { bf16x8 v; __builtin_memcpy(&v, p, 16); return v; }
__device__ __forceinline__ f32x16 mfma32_(bf16x8 a, bf16x8 b, f32x16 c) {
  return __builtin_amdgcn_mfma_f32_32x32x16_bf16(a, b, c, 0, 0, 0);
}

// Fragment-tiled layouts (all attn/GEMM activation loads become base + lane*16B):
// K':  per (b,kvh): [s>>5][d>>4][ lane=(s&31)+32*((d>>3)&1) ][ d&7 ]        (2048 els per 32-key group)
// V':  per (b,kvh): [p>>6][d>>5][ (p>>4)&3 ][ lane=(d&31)+32*((p>>3)&1) ][ p&7 ]   (p = sigma(s), bits 2<->3)
// Q':  [b][s>>5][h][d>>4][ lane=(s&31)+32*((d>>3)&1) ][ d&7 ]
// actF (xb, ab; K=768): [m>>5][k>>4][ lane=(m&31)+32*((k>>3)&1) ][ k&7 ]   (24576 els per 32-row group)
__device__ __forceinline__ int kidx(int b6kvh, int s, int d) {
  return b6kvh * 131072 + (s >> 5) * 2048 + (d >> 4) * 512 +
         ((s & 31) + 32 * ((d >> 3) & 1)) * 8 + (d & 7);
}
__device__ __forceinline__ int qidx(int b, int s, int h, int d) {
  return ((b * 64 + (s >> 5)) * 12 + h) * 2048 + (d >> 4) * 512 +
         ((s & 31) + 32 * ((d >> 3) & 1)) * 8 + (d & 7);
}
__device__ __forceinline__ int vidx(int b6kvh, int d, int p) {
  return b6kvh * 131072 + (p >> 6) * 4096 + (d >> 5) * 2048 + ((p >> 4) & 3) * 512 +
         ((d & 31) + 32 * ((p >> 3) & 1)) * 8 + (p & 7);
}
__device__ __forceinline__ int fidx(int m, int k) {
  return (m >> 5) * 24576 + (k >> 4) * 512 + ((m & 31) + 32 * ((k >> 3) & 1)) * 8 + (k & 7);
}

// ---------- 1) sum(|w|) per matrix ----------
__global__ __launch_bounds__(256) void abssum_kernel(const float* __restrict__ wq, const float* __restrict__ wk,
                                                     const float* __restrict__ wv, const float* __restrict__ wo,
                                                     float* __restrict__ sums) {
  int which = blockIdx.y;
  const float* w = (which == 0) ? wq : (which == 1) ? wk : (which == 2) ? wv : wo;
  int n4 = ((which == 0 || which == 3) ? NQ : NK) >> 2;
  const float4* w4 = (const float4*)w;
  float s = 0.f;
  for (int i = blockIdx.x * blockDim.x + threadIdx.x; i < n4; i += gridDim.x * blockDim.x) {
    float4 v = w4[i];
    s += fabsf(v.x) + fabsf(v.y) + fabsf(v.z) + fabsf(v.w);
  }
  for (int off = 32; off; off >>= 1) s += __shfl_down(s, off);
  __shared__ float ls[4];
  if ((threadIdx.x & 63) == 0) ls[threadIdx.x >> 6] = s;
  __syncthreads();
  if (threadIdx.x == 0) atomicAdd(&sums[which], ls[0] + ls[1] + ls[2] + ls[3]);
}

// ---------- 2) ternary quantize to bf16 {-1,0,1} ----------
__global__ __launch_bounds__(256) void quant_kernel(const float* __restrict__ wq, const float* __restrict__ wk,
                                                    const float* __restrict__ wv, const float* __restrict__ wo,
                                                    const float* __restrict__ sums,
                                                    u16* __restrict__ qw, u16* __restrict__ woq) {
  float thr0 = 0.7f * sums[0] * (1.f / NQ);
  float thr1 = 0.7f * sums[1] * (1.f / NK);
  float thr2 = 0.7f * sums[2] * (1.f / NK);
  float thr3 = 0.7f * sums[3] * (1.f / NQ);
  const int NQKV = NQ + 2 * NK;
  const int total = NQKV + NQ;
  for (int i = blockIdx.x * blockDim.x + threadIdx.x; i < total; i += gridDim.x * blockDim.x) {
    float v, th; u16* dst;
    if (i < NQ)            { v = wq[i];            th = thr0; dst = &qw[i]; }
    else if (i < NQ + NK)  { v = wk[i - NQ];       th = thr1; dst = &qw[i]; }
    else if (i < NQKV)     { v = wv[i - NQ - NK];  th = thr2; dst = &qw[i]; }
    else                   { v = wo[i - NQKV];     th = thr3; dst = &woq[i - NQKV]; }
    float q = (fabsf(v) >= th) ? ((v > 0.f) ? 1.f : -1.f) : 0.f;
    *dst = f2bf(q);
  }
}

// ---------- 3) x -> bf16, fragment-tiled ----------
// thread handles 8 consecutive k of one row m: idx = m*96 + k8.
__global__ __launch_bounds__(256) void castx_kernel(const float* __restrict__ x, u16* __restrict__ xb) {
  int idx = blockIdx.x * blockDim.x + threadIdx.x;   // [0, 4096*96)
  int m = idx / 96, k8 = idx - m * 96;
  const float4* xp = (const float4*)(x + m * 768 + k8 * 8);
  float4 v0 = xp[0], v1 = xp[1];
  u16 o[8] = { f2bf(v0.x), f2bf(v0.y), f2bf(v0.z), f2bf(v0.w),
               f2bf(v1.x), f2bf(v1.y), f2bf(v1.z), f2bf(v1.w) };
  u16* dst = xb + (m >> 5) * 24576 + (k8 >> 1) * 512 + ((m & 31) + 32 * (k8 & 1)) * 8;
  __builtin_memcpy(dst, o, 16);
}

// ---------- shared GEMM core: C[64m x 128n] += A[m][k] * B[n][k], K=768 ----------
// A fragment-tiled (coalesced lane*16B loads). B row-major staged via global_load_lds w/ xor swizzle.
__device__ __forceinline__ void gemm_tile_64x128(const u16* __restrict__ A, const u16* __restrict__ Bw,
                                                 u16* Bt, int tm, int tn, f32x16 acc[2]) {
  int t = threadIdx.x, lane = t & 63, w = t >> 6, c = lane & 31, g2 = lane >> 5;
  int wm = w & 1, wn = w >> 1;
  const u16* abase = A + (tm * 2 + wm) * 24576 + lane * 8;
  for (int k0 = 0; k0 < 768; k0 += 64) {
#pragma unroll
    for (int rd = 0; rd < 4; rd++) {
      int ch = (rd * 4 + w) * 64 + lane;          // 16B chunk index in [0,1024)
      int n = ch >> 3, jp = ch & 7;
      int jl = jp ^ (n & 7);                      // logical k-chunk for this physical slot
      const u16* gp = Bw + (tn * 128 + n) * 768 + k0 + jl * 8;
      __builtin_amdgcn_global_load_lds((const __attribute__((address_space(1))) u32*)gp,
                                       (__attribute__((address_space(3))) u32*)(Bt + (rd * 4 + w) * 512),
                                       16, 0, 0);
    }
    bf16x8 af[4];
#pragma unroll
    for (int ks = 0; ks < 4; ks++) af[ks] = ldfrag(abase + ((k0 >> 4) + ks) * 512);
    __syncthreads();
#pragma unroll
    for (int ks = 0; ks < 4; ks++) {
#pragma unroll
      for (int nb = 0; nb < 2; nb++) {
        int n = wn * 64 + nb * 32 + c;
        int jp = (ks * 2 + g2) ^ (n & 7);
        bf16x8 bf = ldfrag(Bt + n * 64 + jp * 8);
        acc[nb] = mfma32_(af[ks], bf, acc[nb]);
      }
    }
    __syncthreads();
  }
}

// ---------- 4) fused QKV GEMM + scale + RoPE + fragment-tiled outputs ----------
__global__ __launch_bounds__(256, 4) void gemm_qkv_kernel(const u16* __restrict__ xb, const u16* __restrict__ qw,
                                                          const float* __restrict__ sums,
                                                          u16* __restrict__ qb, u16* __restrict__ kb,
                                                          u16* __restrict__ vT) {
  __shared__ u16 Bt[8192];
  int tn = blockIdx.x, tm = blockIdx.y;
  f32x16 acc[2]; acc[0] = (f32x16)0.f; acc[1] = (f32x16)0.f;
  gemm_tile_64x128(xb, qw, Bt, tm, tn, acc);
  int t = threadIdx.x, lane = t & 63, w = t >> 6, c = lane & 31, g2 = lane >> 5;
  int wm = w & 1, wn = w >> 1;
  float sq = sums[0] * (1.f / NQ) * 0.180336880111120f;  // * 0.125 * log2(e)
  float sk = sums[1] * (1.f / NK);
  float sv = sums[2] * (1.f / NK);
  int mb = tm * 64 + wm * 32 + 4 * g2;
  if (tn < 9) {
    float sc = (tn < 6) ? sq : sk;
    int head = (tn < 6) ? (tn * 2 + wn) : ((tn - 6) * 2 + wn);
    float f = fexp2((float)c * -0.41524101186092029f);   // 10000^(-c/32)
#pragma unroll
    for (int r = 0; r < 16; r++) {
      int m = mb + (r & 3) + 8 * (r >> 2);
      int bb = m >> 11, s = m & 2047;
      float sn, cs; sincosf((float)s * f, &sn, &cs);
      float x1 = acc[0][r] * sc, x2 = acc[1][r] * sc;
      u16 y1 = f2bf(x1 * cs - x2 * sn);       // dim d = c
      u16 y2 = f2bf(x2 * cs + x1 * sn);       // dim d = c + 32
      if (tn < 6) {
        qb[qidx(bb, s, head, c)]      = y1;
        qb[qidx(bb, s, head, c + 32)] = y2;
      } else {
        kb[kidx(bb * 6 + head, s, c)]      = y1;
        kb[kidx(bb * 6 + head, s, c + 32)] = y2;
      }
    }
  } else {
    int kvh = (tn - 9) * 2 + wn;
#pragma unroll
    for (int nb = 0; nb < 2; nb++)
#pragma unroll
      for (int r = 0; r < 16; r++) {
        int m = mb + (r & 3) + 8 * (r >> 2);
        int bb = m >> 11, s = m & 2047;
        int sp = (s & ~12) | ((s & 4) << 1) | ((s & 8) >> 1);   // sigma: swap bits 2,3
        vT[vidx(bb * 6 + kvh, nb * 32 + c, sp)] = f2bf(acc[nb][r] * sv);
      }
  }
}

// ---------- 5) attention: one head per wave, 32 keys/iter, lsum via ones-MFMA ----------
// grid (64 qt of 32 q-rows, 12 b*kvh). block 256 = 4 waves: head qn = w&1, key-half kh = w>>1.
// Waves 0,1 read the same K/V tiles (L1 dedupe). Barrier-free main loop; single combine barrier.
__global__ __launch_bounds__(256, 3) void attn_kernel(const u16* __restrict__ qb, const u16* __restrict__ kb,
                                                      const u16* __restrict__ vT, u16* __restrict__ ab) {
  __shared__ float Obuf[4][32][66];
  __shared__ float Lbuf[4][32];
  int qt = blockIdx.x, bk = blockIdx.y;
  int b = bk / 6, kvh = bk % 6;
  int t = threadIdx.x, lane = t & 63, w = t >> 6, c = lane & 31, g2 = lane >> 5;
  int qn = w & 1, kh = w >> 1;

  const u16* qbase = qb + ((b * 64 + qt) * 12 + kvh * 2 + qn) * 2048;
  bf16x8 qf[4];
#pragma unroll
  for (int ks = 0; ks < 4; ks++) qf[ks] = ldfrag(qbase + ks * 512 + lane * 8);

  u32 onesw = 0x3F803F80u;
  bf16x8 ones;
  { u32 tmp[4] = {onesw, onesw, onesw, onesw}; __builtin_memcpy(&ones, tmp, 16); }

  f32x16 fz = (f32x16)0.f;
  f32x16 O[2] = {fz, fz};
  f32x16 Lacc = fz;

  const u16* Kb = kb + bk * 131072;
  const u16* Vb = vT + bk * 131072;

  for (int it = 0; it < 32; it++) {
    int kb32 = kh * 32 + it;                       // 32-key group index
    const u16* kt = Kb + kb32 * 2048;
    const u16* vt = Vb + (kb32 >> 1) * 4096 + (kb32 & 1) * 1024;
    bf16x8 kf[4];
#pragma unroll
    for (int ks = 0; ks < 4; ks++) kf[ks] = ldfrag(kt + ks * 512 + lane * 8);
    bf16x8 vf[2][2];
#pragma unroll
    for (int dn = 0; dn < 2; dn++)
#pragma unroll
      for (int ksv = 0; ksv < 2; ksv++)
        vf[dn][ksv] = ldfrag(vt + dn * 2048 + ksv * 512 + lane * 8);
    f32x16 S = fz;
#pragma unroll
    for (int ks = 0; ks < 4; ks++) S = mfma32_(kf[ks], qf[ks], S);
    float e[16];
#pragma unroll
    for (int r = 0; r < 16; r++) e[r] = fexp2(S[r]);
    u32 P[8];
#pragma unroll
    for (int j = 0; j < 8; j++) P[j] = packbf(e[2 * j], e[2 * j + 1]);
    bf16x8 PA[2];
    __builtin_memcpy(&PA[0], &P[0], 16);
    __builtin_memcpy(&PA[1], &P[4], 16);
#pragma unroll
    for (int ksv = 0; ksv < 2; ksv++) {
      O[0] = mfma32_(PA[ksv], vf[0][ksv], O[0]);
      O[1] = mfma32_(PA[ksv], vf[1][ksv], O[1]);
      Lacc = mfma32_(PA[ksv], ones, Lacc);
    }
  }
  // per-wave results to LDS (Lacc row q = (r&3)+8*(r>>2)+4*g2, value identical across lanes)
  if (c == 0) {
#pragma unroll
    for (int r = 0; r < 16; r++) Lbuf[w][(r & 3) + 8 * (r >> 2) + 4 * g2] = Lacc[r];
  }
#pragma unroll
  for (int dn = 0; dn < 2; dn++)
#pragma unroll
    for (int r = 0; r < 16; r++)
      Obuf[w][(r & 3) + 8 * (r >> 2) + 4 * g2][dn * 32 + c] = O[dn][r];
  __syncthreads();
  // combine the two key-half waves of each head; write ab fragment-tiled
  {
    int hn = t >> 7, qq = (t >> 2) & 31, dc = (t & 3) * 16;
    float l = Lbuf[hn][qq] + Lbuf[hn + 2][qq];
    float inv = 1.f / l;
    u16 o[16];
#pragma unroll
    for (int j = 0; j < 16; j++)
      o[j] = f2bf((Obuf[hn][qq][dc + j] + Obuf[hn + 2][qq][dc + j]) * inv);
    int h = kvh * 2 + hn;
    int mg = b * 64 + qt;
    u16* dst = ab + mg * 24576 + ((h * 64 + dc) >> 4) * 512 + qq * 8;
    __builtin_memcpy(dst, o, 16);            // d8-group (dc>>3)&1 == 0
    __builtin_memcpy(dst + 256, o + 8, 16);  // d8-group 1: +32*8 els
  }
}

// ---------- 6) output projection GEMM (64x64 tiles) -> fp32 ----------
__global__ __launch_bounds__(256, 4) void gemm_out_kernel(const u16* __restrict__ ab, const u16* __restrict__ woq,
                                                          const float* __restrict__ sums, float* __restrict__ out) {
  __shared__ u16 Bt[4096];
  int tn = blockIdx.x, tm = blockIdx.y;
  int t = threadIdx.x, lane = t & 63, w = t >> 6, c = lane & 31, g2 = lane >> 5;
  int wm = w & 1, wn = w >> 1;
  f32x16 acc = (f32x16)0.f;
  const u16* abase = ab + (tm * 2 + wm) * 24576 + lane * 8;
  for (int k0 = 0; k0 < 768; k0 += 64) {
#pragma unroll
    for (int rd = 0; rd < 2; rd++) {
      int ch = (rd * 4 + w) * 64 + lane;          // 16B chunk index in [0,512)
      int n = ch >> 3, jp = ch & 7;
      int jl = jp ^ (n & 7);
      const u16* gp = woq + (tn * 64 + n) * 768 + k0 + jl * 8;
      __builtin_amdgcn_global_load_lds((const __attribute__((address_space(1))) u32*)gp,
                                       (__attribute__((address_space(3))) u32*)(Bt + (rd * 4 + w) * 512),
                                       16, 0, 0);
    }
    bf16x8 af[4];
#pragma unroll
    for (int ks = 0; ks < 4; ks++) af[ks] = ldfrag(abase + ((k0 >> 4) + ks) * 512);
    __syncthreads();
#pragma unroll
    for (int ks = 0; ks < 4; ks++) {
      int n = wn * 32 + c;
      int jp = (ks * 2 + g2) ^ (n & 7);
      bf16x8 bf = ldfrag(Bt + n * 64 + jp * 8);
      acc = mfma32_(af[ks], bf, acc);
    }
    __syncthreads();
  }
  float so = sums[3] * (1.f / NQ);
  int mb = tm * 64 + wm * 32 + 4 * g2;
#pragma unroll
  for (int r = 0; r < 16; r++) {
    int m = mb + (r & 3) + 8 * (r >> 2);
    out[m * 768 + tn * 64 + wn * 32 + c] = acc[r] * so;
  }
}

// ---------- launch ----------
extern "C" void kernel_launch(void* const* d_in, const int* in_sizes, int n_in,
                              void* d_out, int out_size, void* d_ws, size_t ws_size,
                              hipStream_t stream) {
  const float* x  = (const float*)d_in[0];
  const float* wq = (const float*)d_in[1];
  const float* wk = (const float*)d_in[2];
  const float* wv = (const float*)d_in[3];
  const float* wo = (const float*)d_in[4];
  float* out = (float*)d_out;
  char* ws = (char*)d_ws;

  float* sums = (float*)ws;                    // 16 B
  u16* qw  = (u16*)(ws + 256);                 // [1536][768]
  u16* woq = (u16*)(ws + 2359552);             // [768][768]
  u16* xb  = (u16*)(ws + 3539200);             // x fragment-tiled (3.1M els)
  u16* qb  = (u16*)(ws + 9830656);             // Q' fragment-tiled (3.1M els)
  u16* kb  = (u16*)(ws + 16122112);            // K' fragment-tiled (1.57M els)
  u16* vT  = (u16*)(ws + 19267840);            // V' fragment-tiled, key-permuted (1.57M els)
  u16* ab  = (u16*)(ws + 22413568);            // attn out fragment-tiled (3.1M els)

  hipMemsetAsync(sums, 0, 16, stream);
  dim3 blk(256);
  abssum_kernel<<<dim3(64, 4), blk, 0, stream>>>(wq, wk, wv, wo, sums);
  quant_kernel<<<dim3(6912), blk, 0, stream>>>(wq, wk, wv, wo, sums, qw, woq);
  castx_kernel<<<dim3(1536), blk, 0, stream>>>(x, xb);
  gemm_qkv_kernel<<<dim3(12, 64), blk, 0, stream>>>(xb, qw, sums, qb, kb, vT);
  attn_kernel<<<dim3(64, 12), blk, 0, stream>>>(qb, kb, vT, ab);
  gemm_out_kernel<<<dim3(12, 64), blk, 0, stream>>>(ab, woq, sums, out);
}

// Round 8
// 156.913 us; speedup vs baseline: 1.4405x; 1.0035x over previous
//
#include <hip/hip_runtime.h>
#include <cmath>

typedef unsigned short u16;
typedef unsigned int u32;
typedef __bf16 bf16x2 __attribute__((ext_vector_type(2)));
typedef __bf16 bf16x8 __attribute__((ext_vector_type(8)));
typedef float f32x16 __attribute__((ext_vector_type(16)));

#define NQ (768*768)
#define NK (384*768)

// ---------- helpers ----------
__device__ __forceinline__ u16 f2bf(float f) {
  u32 u = __float_as_uint(f);
  u32 r = (u + 0x7FFFu + ((u >> 16) & 1u)) >> 16;  // RNE
  return (u16)r;
}
__device__ __forceinline__ u32 packbf(float a, float b) {
#if __has_builtin(__builtin_amdgcn_cvt_pk_bf16_f32)
  bf16x2 v = __builtin_amdgcn_cvt_pk_bf16_f32(a, b);
  u32 r; __builtin_memcpy(&r, &v, 4); return r;
#else
  return (u32)f2bf(a) | ((u32)f2bf(b) << 16);
#endif
}
__device__ __forceinline__ float fexp2(float x) {
#if __has_builtin(__builtin_amdgcn_exp2f)
  return __builtin_amdgcn_exp2f(x);
#else
  return exp2f(x);
#endif
}
__device__ __forceinline__ bf16x8 ldfrag(const u16* p) { bf16x8 v; __builtin_memcpy(&v, p, 16); return v; }
__device__ __forceinline__ f32x16 mfma32_(bf16x8 a, bf16x8 b, f32x16 c) {
  return __builtin_amdgcn_mfma_f32_32x32x16_bf16(a, b, c, 0, 0, 0);
}

// Fragment-tiled layouts (ALL GEMM/attn operand loads become base + lane*16B, coalesced):
// actF / wF (K=768): [r>>5][k>>4][ lane=(r&31)+32*((k>>3)&1) ][ k&7 ]  (24576 els per 32-row group)
// K':  per (b,kvh): [s>>5][d>>4][ lane=(s&31)+32*((d>>3)&1) ][ d&7 ]
// V':  per (b,kvh): [p>>6][d>>5][ (p>>4)&3 ][ lane=(d&31)+32*((p>>3)&1) ][ p&7 ]  (p = sigma(s), bits 2<->3)
// Q':  [b][s>>5][h][d>>4][ lane=(s&31)+32*((d>>3)&1) ][ d&7 ]
__device__ __forceinline__ int fidx(int r, int k) {
  return (r >> 5) * 24576 + (k >> 4) * 512 + ((r & 31) + 32 * ((k >> 3) & 1)) * 8 + (k & 7);
}
__device__ __forceinline__ int kidx(int b6kvh, int s, int d) {
  return b6kvh * 131072 + (s >> 5) * 2048 + (d >> 4) * 512 +
         ((s & 31) + 32 * ((d >> 3) & 1)) * 8 + (d & 7);
}
__device__ __forceinline__ int qidx(int b, int s, int h, int d) {
  return ((b * 64 + (s >> 5)) * 12 + h) * 2048 + (d >> 4) * 512 +
         ((s & 31) + 32 * ((d >> 3) & 1)) * 8 + (d & 7);
}
__device__ __forceinline__ int vidx(int b6kvh, int d, int p) {
  return b6kvh * 131072 + (p >> 6) * 4096 + (d >> 5) * 2048 + ((p >> 4) & 3) * 512 +
         ((d & 31) + 32 * ((p >> 3) & 1)) * 8 + (p & 7);
}

// ---------- 1) sum(|w|) per matrix ----------
__global__ __launch_bounds__(256) void abssum_kernel(const float* __restrict__ wq, const float* __restrict__ wk,
                                                     const float* __restrict__ wv, const float* __restrict__ wo,
                                                     float* __restrict__ sums) {
  int which = blockIdx.y;
  const float* w = (which == 0) ? wq : (which == 1) ? wk : (which == 2) ? wv : wo;
  int n4 = ((which == 0 || which == 3) ? NQ : NK) >> 2;
  const float4* w4 = (const float4*)w;
  float s = 0.f;
  for (int i = blockIdx.x * blockDim.x + threadIdx.x; i < n4; i += gridDim.x * blockDim.x) {
    float4 v = w4[i];
    s += fabsf(v.x) + fabsf(v.y) + fabsf(v.z) + fabsf(v.w);
  }
  for (int off = 32; off; off >>= 1) s += __shfl_down(s, off);
  __shared__ float ls[4];
  if ((threadIdx.x & 63) == 0) ls[threadIdx.x >> 6] = s;
  __syncthreads();
  if (threadIdx.x == 0) atomicAdd(&sums[which], ls[0] + ls[1] + ls[2] + ls[3]);
}

// ---------- 2) prep: ternary-quantize weights into fragment-tiled layout + cast x ----------
// items 0 .. 221184: weight row n (0-1535 -> qw rows, 1536-2303 -> woq), 8 k per thread.
// items 221184 .. 614400: x row m, 8 k per thread.
__global__ __launch_bounds__(256) void prep_kernel(const float* __restrict__ wq, const float* __restrict__ wk,
                                                   const float* __restrict__ wv, const float* __restrict__ wo,
                                                   const float* __restrict__ sums, const float* __restrict__ x,
                                                   u16* __restrict__ qw, u16* __restrict__ woq,
                                                   u16* __restrict__ xb) {
  int i = blockIdx.x * blockDim.x + threadIdx.x;
  if (i < 221184) {
    int n = i / 96, k8 = i - n * 96;
    const float* src; float th; u16* dst; int nd;
    if (n < 768)       { src = wq + n * 768;          th = 0.7f * sums[0] * (1.f / NQ); dst = qw;  nd = n; }
    else if (n < 1152) { src = wk + (n - 768) * 768;  th = 0.7f * sums[1] * (1.f / NK); dst = qw;  nd = n; }
    else if (n < 1536) { src = wv + (n - 1152) * 768; th = 0.7f * sums[2] * (1.f / NK); dst = qw;  nd = n; }
    else               { src = wo + (n - 1536) * 768; th = 0.7f * sums[3] * (1.f / NQ); dst = woq; nd = n - 1536; }
    const float4* sp = (const float4*)(src + k8 * 8);
    float4 v0 = sp[0], v1 = sp[1];
    float e[8] = {v0.x, v0.y, v0.z, v0.w, v1.x, v1.y, v1.z, v1.w};
    u16 o[8];
#pragma unroll
    for (int j = 0; j < 8; j++)
      o[j] = f2bf((fabsf(e[j]) >= th) ? ((e[j] > 0.f) ? 1.f : -1.f) : 0.f);
    __builtin_memcpy(dst + fidx(nd, k8 * 8), o, 16);
  } else {
    int j = i - 221184;
    int m = j / 96, k8 = j - m * 96;
    const float4* xp = (const float4*)(x + m * 768 + k8 * 8);
    float4 v0 = xp[0], v1 = xp[1];
    u16 o[8] = { f2bf(v0.x), f2bf(v0.y), f2bf(v0.z), f2bf(v0.w),
                 f2bf(v1.x), f2bf(v1.y), f2bf(v1.z), f2bf(v1.w) };
    __builtin_memcpy(xb + fidx(m, k8 * 8), o, 16);
  }
}

// ---------- 3) fused QKV GEMM (barrier-free, no LDS) + scale + RoPE + tiled outputs ----------
// 64m x 128n tile, wm = w&1 (m-half), wn = w>>1 (n-half = one head's 64 cols for Q/K regions).
__global__ __launch_bounds__(256, 3) void gemm_qkv_kernel(const u16* __restrict__ xb, const u16* __restrict__ qw,
                                                          const float* __restrict__ sums,
                                                          u16* __restrict__ qb, u16* __restrict__ kb,
                                                          u16* __restrict__ vT) {
  int tn = blockIdx.x, tm = blockIdx.y;
  int t = threadIdx.x, lane = t & 63, w = t >> 6, c = lane & 31, g2 = lane >> 5;
  int wm = w & 1, wn = w >> 1;
  const u16* abase = xb + (tm * 2 + wm) * 24576 + lane * 8;
  const u16* bbase0 = qw + (tn * 4 + wn * 2) * 24576 + lane * 8;
  const u16* bbase1 = bbase0 + 24576;
  f32x16 acc[2]; acc[0] = (f32x16)0.f; acc[1] = (f32x16)0.f;
  for (int kk = 0; kk < 48; kk += 4) {
#pragma unroll
    for (int ks = 0; ks < 4; ks++) {
      bf16x8 af = ldfrag(abase + (kk + ks) * 512);
      bf16x8 b0 = ldfrag(bbase0 + (kk + ks) * 512);
      bf16x8 b1 = ldfrag(bbase1 + (kk + ks) * 512);
      acc[0] = mfma32_(af, b0, acc[0]);
      acc[1] = mfma32_(af, b1, acc[1]);
    }
  }
  float sq = sums[0] * (1.f / NQ) * 0.180336880111120f;  // * 0.125 * log2(e)
  float sk = sums[1] * (1.f / NK);
  float sv = sums[2] * (1.f / NK);
  int mb = tm * 64 + wm * 32 + 4 * g2;
  if (tn < 9) {
    float sc = (tn < 6) ? sq : sk;
    int head = (tn < 6) ? (tn * 2 + wn) : ((tn - 6) * 2 + wn);
    float f = fexp2((float)c * -0.41524101186092029f);   // 10000^(-c/32)
#pragma unroll
    for (int r = 0; r < 16; r++) {
      int m = mb + (r & 3) + 8 * (r >> 2);
      int bb = m >> 11, s = m & 2047;
      float sn, cs; sincosf((float)s * f, &sn, &cs);
      float x1 = acc[0][r] * sc, x2 = acc[1][r] * sc;
      u16 y1 = f2bf(x1 * cs - x2 * sn);       // dim d = c
      u16 y2 = f2bf(x2 * cs + x1 * sn);       // dim d = c + 32
      if (tn < 6) {
        qb[qidx(bb, s, head, c)]      = y1;
        qb[qidx(bb, s, head, c + 32)] = y2;
      } else {
        kb[kidx(bb * 6 + head, s, c)]      = y1;
        kb[kidx(bb * 6 + head, s, c + 32)] = y2;
      }
    }
  } else {
    int kvh = (tn - 9) * 2 + wn;
#pragma unroll
    for (int nb = 0; nb < 2; nb++)
#pragma unroll
      for (int r = 0; r < 16; r++) {
        int m = mb + (r & 3) + 8 * (r >> 2);
        int bb = m >> 11, s = m & 2047;
        int sp = (s & ~12) | ((s & 4) << 1) | ((s & 8) >> 1);   // sigma: swap bits 2,3
        vT[vidx(bb * 6 + kvh, nb * 32 + c, sp)] = f2bf(acc[nb][r] * sv);
      }
  }
}

// ---------- 4) attention: one head per wave, 32 keys/iter, lsum via ones-MFMA ----------
// grid (12 b*kvh, 64 qt): bk fastest -> consecutive blocks hit different XCDs, each XCD's L2
// stays hot on ~1.5 K/V sets. block 256 = 4 waves: head qn = w&1, key-half kh = w>>1.
__global__ __launch_bounds__(256, 3) void attn_kernel(const u16* __restrict__ qb, const u16* __restrict__ kb,
                                                      const u16* __restrict__ vT, u16* __restrict__ ab) {
  __shared__ float Obuf[4][32][66];
  __shared__ float Lbuf[4][32];
  int bk = blockIdx.x, qt = blockIdx.y;
  int b = bk / 6, kvh = bk % 6;
  int t = threadIdx.x, lane = t & 63, w = t >> 6, c = lane & 31, g2 = lane >> 5;
  int qn = w & 1, kh = w >> 1;

  const u16* qbase = qb + ((b * 64 + qt) * 12 + kvh * 2 + qn) * 2048;
  bf16x8 qf[4];
#pragma unroll
  for (int ks = 0; ks < 4; ks++) qf[ks] = ldfrag(qbase + ks * 512 + lane * 8);

  u32 onesw = 0x3F803F80u;
  bf16x8 ones;
  { u32 tmp[4] = {onesw, onesw, onesw, onesw}; __builtin_memcpy(&ones, tmp, 16); }

  f32x16 fz = (f32x16)0.f;
  f32x16 O[2] = {fz, fz};
  f32x16 Lacc = fz;

  const u16* Kb = kb + bk * 131072;
  const u16* Vb = vT + bk * 131072;

  for (int it = 0; it < 32; it++) {
    int kb32 = kh * 32 + it;                       // 32-key group index
    const u16* kt = Kb + kb32 * 2048;
    const u16* vt = Vb + (kb32 >> 1) * 4096 + (kb32 & 1) * 1024;
    bf16x8 kf[4];
#pragma unroll
    for (int ks = 0; ks < 4; ks++) kf[ks] = ldfrag(kt + ks * 512 + lane * 8);
    bf16x8 vf[2][2];
#pragma unroll
    for (int dn = 0; dn < 2; dn++)
#pragma unroll
      for (int ksv = 0; ksv < 2; ksv++)
        vf[dn][ksv] = ldfrag(vt + dn * 2048 + ksv * 512 + lane * 8);
    f32x16 S = fz;
#pragma unroll
    for (int ks = 0; ks < 4; ks++) S = mfma32_(kf[ks], qf[ks], S);
    float e[16];
#pragma unroll
    for (int r = 0; r < 16; r++) e[r] = fexp2(S[r]);
    u32 P[8];
#pragma unroll
    for (int j = 0; j < 8; j++) P[j] = packbf(e[2 * j], e[2 * j + 1]);
    bf16x8 PA[2];
    __builtin_memcpy(&PA[0], &P[0], 16);
    __builtin_memcpy(&PA[1], &P[4], 16);
#pragma unroll
    for (int ksv = 0; ksv < 2; ksv++) {
      O[0] = mfma32_(PA[ksv], vf[0][ksv], O[0]);
      O[1] = mfma32_(PA[ksv], vf[1][ksv], O[1]);
      Lacc = mfma32_(PA[ksv], ones, Lacc);
    }
  }
  if (c == 0) {
#pragma unroll
    for (int r = 0; r < 16; r++) Lbuf[w][(r & 3) + 8 * (r >> 2) + 4 * g2] = Lacc[r];
  }
#pragma unroll
  for (int dn = 0; dn < 2; dn++)
#pragma unroll
    for (int r = 0; r < 16; r++)
      Obuf[w][(r & 3) + 8 * (r >> 2) + 4 * g2][dn * 32 + c] = O[dn][r];
  __syncthreads();
  {
    int hn = t >> 7, qq = (t >> 2) & 31, dc = (t & 3) * 16;
    float l = Lbuf[hn][qq] + Lbuf[hn + 2][qq];
    float inv = 1.f / l;
    u16 o[16];
#pragma unroll
    for (int j = 0; j < 16; j++)
      o[j] = f2bf((Obuf[hn][qq][dc + j] + Obuf[hn + 2][qq][dc + j]) * inv);
    int h = kvh * 2 + hn;
    int mg = b * 64 + qt;
    u16* dst = ab + mg * 24576 + ((h * 64 + dc) >> 4) * 512 + qq * 8;
    __builtin_memcpy(dst, o, 16);            // d8-group 0
    __builtin_memcpy(dst + 256, o + 8, 16);  // d8-group 1
  }
}

// ---------- 5) output projection GEMM (barrier-free, no LDS, 64m x 64n) -> fp32 ----------
__global__ __launch_bounds__(256, 3) void gemm_out_kernel(const u16* __restrict__ ab, const u16* __restrict__ woq,
                                                          const float* __restrict__ sums, float* __restrict__ out) {
  int tn = blockIdx.x, tm = blockIdx.y;
  int t = threadIdx.x, lane = t & 63, w = t >> 6, c = lane & 31, g2 = lane >> 5;
  int wm = w & 1, wn = w >> 1;
  const u16* abase = ab + (tm * 2 + wm) * 24576 + lane * 8;
  const u16* bbase = woq + (tn * 2 + wn) * 24576 + lane * 8;
  f32x16 acc = (f32x16)0.f;
  for (int kk = 0; kk < 48; kk += 4) {
#pragma unroll
    for (int ks = 0; ks < 4; ks++) {
      bf16x8 af = ldfrag(abase + (kk + ks) * 512);
      bf16x8 bf = ldfrag(bbase + (kk + ks) * 512);
      acc = mfma32_(af, bf, acc);
    }
  }
  float so = sums[3] * (1.f / NQ);
  int mb = tm * 64 + wm * 32 + 4 * g2;
#pragma unroll
  for (int r = 0; r < 16; r++) {
    int m = mb + (r & 3) + 8 * (r >> 2);
    out[m * 768 + tn * 64 + wn * 32 + c] = acc[r] * so;
  }
}

// ---------- launch ----------
extern "C" void kernel_launch(void* const* d_in, const int* in_sizes, int n_in,
                              void* d_out, int out_size, void* d_ws, size_t ws_size,
                              hipStream_t stream) {
  const float* x  = (const float*)d_in[0];
  const float* wq = (const float*)d_in[1];
  const float* wk = (const float*)d_in[2];
  const float* wv = (const float*)d_in[3];
  const float* wo = (const float*)d_in[4];
  float* out = (float*)d_out;
  char* ws = (char*)d_ws;

  float* sums = (float*)ws;                    // 16 B
  u16* qw  = (u16*)(ws + 256);                 // ternary QKV weights, fragment-tiled (1536 rows)
  u16* woq = (u16*)(ws + 2359552);             // ternary O weights, fragment-tiled (768 rows)
  u16* xb  = (u16*)(ws + 3539200);             // x fragment-tiled
  u16* qb  = (u16*)(ws + 9830656);             // Q' fragment-tiled
  u16* kb  = (u16*)(ws + 16122112);            // K' fragment-tiled
  u16* vT  = (u16*)(ws + 19267840);            // V' fragment-tiled, key-permuted
  u16* ab  = (u16*)(ws + 22413568);            // attn out fragment-tiled

  hipMemsetAsync(sums, 0, 16, stream);
  dim3 blk(256);
  abssum_kernel<<<dim3(64, 4), blk, 0, stream>>>(wq, wk, wv, wo, sums);
  prep_kernel<<<dim3(2400), blk, 0, stream>>>(wq, wk, wv, wo, sums, x, qw, woq, xb);
  gemm_qkv_kernel<<<dim3(12, 64), blk, 0, stream>>>(xb, qw, sums, qb, kb, vT);
  attn_kernel<<<dim3(12, 64), blk, 0, stream>>>(qb, kb, vT, ab);
  gemm_out_kernel<<<dim3(12, 64), blk, 0, stream>>>(ab, woq, sums, out);
}